// Round 7
// baseline (47023.978 us; speedup 1.0000x reference)
//
#include <hip/hip_runtime.h>
#include <hip/hip_bf16.h>

// ============================================================================
// 2-layer quirky LSTM, persistent kernel, round 7.
// Numerics (frozen since r3): double-bf16 (hi+lo) for W, h, x; f32 c.
// r6 lesson: latency-bound with MLP~5 (VGPR=80, compiler JIT-loads). This
// round: explicit register-batched prefetch — 8-chunk blocks issue 40 global
// loads into static unrolled register arrays before the 72 consuming MFMAs
// (counted vmcnt -> MLP~40/wave). Memory plan unchanged from r6:
//  - W-lo in LDS (lane-linear, conflict-free), W-hi L2-resident
//  - h ring depth 16, sc1 producer stores, plain consumer loads,
//    acquire-inv fence once per 16 phases; master-WG barrier.
// ============================================================================

typedef __attribute__((ext_vector_type(8))) short bf16x8;
typedef __attribute__((ext_vector_type(4))) float f32x4;
typedef unsigned long long u64;
#define DEV __device__ __forceinline__

namespace {
constexpr int Bb = 128, Ss = 1024, Ii = 512, Hh = 1024;
constexpr int K0 = Ii + Hh;            // 1536
constexpr int K1 = 2 * Hh;             // 2048
constexpr int NWG = 256;               // 1 WG/CU, 512 threads
constexpr int NPH = Ss + 1;
constexpr int RING = 16;               // h ring depth (= inv period)

constexpr size_t BH    = (size_t)Bb * Hh;              // 131072
constexpr size_t OF_H0 = (size_t)Bb * Ss * Hh;
constexpr size_t OF_C0 = OF_H0 + BH;
constexpr size_t OF_H1 = OF_C0 + BH;
constexpr size_t OF_C1 = OF_H1 + BH;

// workspace
constexpr size_t WS_GO    = 0;
constexpr size_t WS_SLOTS = 256;                     // 256 ints
constexpr size_t WS_C0    = 4096;                    // f32 [B][H]
constexpr size_t WS_C1    = WS_C0 + BH * 4;
constexpr size_t RINGB    = (size_t)RING * BH * 2;   // 4 MB per plane
constexpr size_t WS_H0HI  = WS_C1 + BH * 4;
constexpr size_t WS_H0LO  = WS_H0HI + RINGB;
constexpr size_t WS_H1HI  = WS_H0LO + RINGB;
constexpr size_t WS_H1LO  = WS_H1HI + RINGB;
constexpr size_t WS_ZEND  = WS_H1LO + RINGB;         // ~17.8 MB zeroed/launch
constexpr size_t WSZ_W0   = (size_t)3 * Hh * K0 * 2;
constexpr size_t WSZ_W1   = (size_t)3 * Hh * K1 * 2;
constexpr size_t WS_W0H   = WS_ZEND;
constexpr size_t WS_W1H   = WS_W0H + WSZ_W0;
constexpr size_t WS_W0L   = WS_W1H + WSZ_W1;
constexpr size_t WS_W1L   = WS_W0L + WSZ_W0;
constexpr size_t WS_NEED  = WS_W1L + WSZ_W1;         // ~59 MB
constexpr size_t WS_HIEND = WS_W0L;                  // hi-only fallback

// LDS W-lo: [48 k-chunks][3 gates][4 l4][16 l15][16B]  (3072 B per chunk)
constexpr int CHUNKB    = 3072;
constexpr int LO_K      = 1536;
constexpr int LO_BYTES  = 48 * CHUNKB;              // 147456
constexpr int RED_BYTES = 4 * 3 * 64 * 16;          // 12288
constexpr int DYN_LDS   = LO_BYTES + RED_BYTES;     // 159744 <= 160 KiB
}

DEV unsigned short bf16r(float f) {
  return __builtin_bit_cast(unsigned short, __float2bfloat16(f));
}
DEV float bf2f(unsigned short u) {
  unsigned int x = (unsigned int)u << 16;
  return __builtin_bit_cast(float, x);
}
DEV float sig_(float x) { return 1.f / (1.f + __expf(-x)); }
DEV float tanh_(float x) {
  float e = __expf(-2.f * fabsf(x));
  return copysignf((1.f - e) / (1.f + e), x);
}
DEV bf16x8 ld16(const unsigned short* p) { return *reinterpret_cast<const bf16x8*>(p); }
#define MFMA __builtin_amdgcn_mfma_f32_16x16x32_bf16

// ---------------------------------------------------------------------------
__global__ void k_zero(uint4* p, int n16) {
  for (int i = blockIdx.x * blockDim.x + threadIdx.x; i < n16; i += gridDim.x * blockDim.x)
    p[i] = make_uint4(0u, 0u, 0u, 0u);
}

template <bool WLO>
__global__ void k_convert(const float* __restrict__ W0, const float* __restrict__ W1,
                          unsigned short* __restrict__ w0h, unsigned short* __restrict__ w0l,
                          unsigned short* __restrict__ w1h, unsigned short* __restrict__ w1l) {
  const long NW04 = (long)3 * Hh * K0 / 4;
  const long NW14 = (long)3 * Hh * K1 / 4;
  const long total = NW04 + NW14;
  for (long i = (long)blockIdx.x * blockDim.x + threadIdx.x; i < total;
       i += (long)gridDim.x * blockDim.x) {
    long e; const float* src; unsigned short *dh, *dl;
    if (i < NW04) { e = i * 4;          src = W0 + e; dh = w0h + e; dl = w0l + e; }
    else          { e = (i - NW04) * 4; src = W1 + e; dh = w1h + e; dl = w1l + e; }
    f32x4 v = *(const f32x4*)src;
    u64 ph = 0, pl = 0;
#pragma unroll
    for (int e2 = 0; e2 < 4; ++e2) {
      unsigned short hi = bf16r(v[e2]);
      ph |= (u64)hi << (16 * e2);
      if (WLO) pl |= (u64)bf16r(v[e2] - bf2f(hi)) << (16 * e2);
    }
    *(u64*)dh = ph;
    if (WLO) *(u64*)dl = pl;
  }
}

// ---------------------------------------------------------------------------
// W-lo fragment from LDS (lane-linear, conflict-free); kl multiple of 32
#define LD_LO(g, kl)                                                          \
  (*(const bf16x8*)(lds + ((kl) >> 5) * CHUNKB + (g) * 1024 + l4 * 256 + l15 * 16))

// MFMA bundle for one chunk: 6 global-plane + 3 LDS-lo products
#define CHUNK_MFMA(wAe, wBe, wCe, ahi, alo, ko_, I, G, O)                     \
  do {                                                                        \
    I = MFMA((wAe), (ahi), I, 0, 0, 0);                                       \
    G = MFMA((wBe), (ahi), G, 0, 0, 0);                                       \
    O = MFMA((wCe), (ahi), O, 0, 0, 0);                                       \
    I = MFMA((wAe), (alo), I, 0, 0, 0);                                       \
    G = MFMA((wBe), (alo), G, 0, 0, 0);                                       \
    O = MFMA((wCe), (alo), O, 0, 0, 0);                                       \
    if constexpr (WLO) {                                                      \
      I = MFMA(LD_LO(0, (ko_)), (ahi), I, 0, 0, 0);                           \
      G = MFMA(LD_LO(1, (ko_)), (ahi), G, 0, 0, 0);                           \
      O = MFMA(LD_LO(2, (ko_)), (ahi), O, 0, 0, 0);                           \
    }                                                                         \
  } while (0)

// 8-chunk block: 40 global loads batched into registers, then 72 MFMAs
#define BLOCK8_L(hiP, loP, kaB, koB)                                          \
  do {                                                                        \
    bf16x8 wA[8], wB[8], wC[8], aH[8], aL[8];                                 \
    _Pragma("unroll") for (int c8 = 0; c8 < 8; ++c8) {                        \
      const int ko_ = (koB) + c8 * 32, ka_ = (kaB) + c8 * 32;                 \
      wA[c8] = ld16(whi + off0 + ko_);                                        \
      wB[c8] = ld16(whi + off1 + ko_);                                        \
      wC[c8] = ld16(whi + off2 + ko_);                                        \
      aH[c8] = ld16((hiP) + ka_);                                             \
      aL[c8] = ld16((loP) + ka_);                                             \
    }                                                                         \
    _Pragma("unroll") for (int c8 = 0; c8 < 8; ++c8) {                        \
      const int ko_ = (koB) + c8 * 32;                                        \
      f32x4 &I = (c8 & 1) ? aI1 : aI0;                                        \
      f32x4 &G = (c8 & 1) ? aG1 : aG0;                                        \
      f32x4 &O = (c8 & 1) ? aO1 : aO0;                                        \
      CHUNK_MFMA(wA[c8], wB[c8], wC[c8], aH[c8], aL[c8], ko_, I, G, O);       \
    }                                                                         \
  } while (0)

// 4-chunk block with W-lo ALSO from global (L1 K-tail >= LO_K): 32 loads
#define BLOCK4_G(hiP, loP, kaB, koB)                                          \
  do {                                                                        \
    bf16x8 wA[4], wB[4], wC[4], lA[4], lB[4], lC[4], aH[4], aL[4];            \
    _Pragma("unroll") for (int c4 = 0; c4 < 4; ++c4) {                        \
      const int ko_ = (koB) + c4 * 32, ka_ = (kaB) + c4 * 32;                 \
      wA[c4] = ld16(whi + off0 + ko_);                                        \
      wB[c4] = ld16(whi + off1 + ko_);                                        \
      wC[c4] = ld16(whi + off2 + ko_);                                        \
      lA[c4] = ld16(wlo + off0 + ko_);                                        \
      lB[c4] = ld16(wlo + off1 + ko_);                                        \
      lC[c4] = ld16(wlo + off2 + ko_);                                        \
      aH[c4] = ld16((hiP) + ka_);                                             \
      aL[c4] = ld16((loP) + ka_);                                             \
    }                                                                         \
    _Pragma("unroll") for (int c4 = 0; c4 < 4; ++c4) {                        \
      f32x4 &I = (c4 & 1) ? aI1 : aI0;                                        \
      f32x4 &G = (c4 & 1) ? aG1 : aG0;                                        \
      f32x4 &O = (c4 & 1) ? aO1 : aO0;                                        \
      I = MFMA(wA[c4], aH[c4], I, 0, 0, 0);                                   \
      G = MFMA(wB[c4], aH[c4], G, 0, 0, 0);                                   \
      O = MFMA(wC[c4], aH[c4], O, 0, 0, 0);                                   \
      I = MFMA(wA[c4], aL[c4], I, 0, 0, 0);                                   \
      G = MFMA(wB[c4], aL[c4], G, 0, 0, 0);                                   \
      O = MFMA(wC[c4], aL[c4], O, 0, 0, 0);                                   \
      I = MFMA(lA[c4], aH[c4], I, 0, 0, 0);                                   \
      G = MFMA(lB[c4], aH[c4], G, 0, 0, 0);                                   \
      O = MFMA(lC[c4], aH[c4], O, 0, 0, 0);                                   \
    }                                                                         \
  } while (0)

// 4-chunk x block: f32 x -> on-the-fly hi/lo bf16; 28 loads batched
#define BLOCK4_X(pxP, kB)                                                     \
  do {                                                                        \
    f32x4 x0_[4], x1_[4], f0_[4], f1_[4];                                     \
    bf16x8 wA[4], wB[4], wC[4];                                               \
    _Pragma("unroll") for (int c4 = 0; c4 < 4; ++c4) {                        \
      const int k_ = (kB) + c4 * 32;                                          \
      x0_[c4] = *(const f32x4*)((pxP) + k_);                                  \
      x1_[c4] = *(const f32x4*)((pxP) + k_ + 4);                              \
      f0_[c4] = *(const f32x4*)(fw + k_ + l4 * 8);                            \
      f1_[c4] = *(const f32x4*)(fw + k_ + l4 * 8 + 4);                        \
      wA[c4] = ld16(whi + off0 + k_);                                         \
      wB[c4] = ld16(whi + off1 + k_);                                         \
      wC[c4] = ld16(whi + off2 + k_);                                         \
    }                                                                         \
    _Pragma("unroll") for (int c4 = 0; c4 < 4; ++c4) {                        \
      const int k_ = (kB) + c4 * 32;                                          \
      f32x4 xs0 = x0_[c4] * f0_[c4] * twm, xs1 = x1_[c4] * f1_[c4] * twm;     \
      bf16x8 ahi, alo;                                                        \
      _Pragma("unroll") for (int e = 0; e < 4; ++e) {                         \
        unsigned short h0_ = bf16r(xs0[e]), h1_ = bf16r(xs1[e]);              \
        ahi[e] = (short)h0_; ahi[e + 4] = (short)h1_;                         \
        alo[e] = (short)bf16r(xs0[e] - bf2f(h0_));                            \
        alo[e + 4] = (short)bf16r(xs1[e] - bf2f(h1_));                        \
      }                                                                       \
      f32x4 &I = (c4 & 1) ? aI1 : aI0;                                        \
      f32x4 &G = (c4 & 1) ? aG1 : aG0;                                        \
      f32x4 &O = (c4 & 1) ? aO1 : aO0;                                        \
      CHUNK_MFMA(wA[c4], wB[c4], wC[c4], ahi, alo, k_, I, G, O);              \
    }                                                                         \
  } while (0)

template <bool WLO>
__global__ __launch_bounds__(512, 2) void lstm_persist(
    const float* __restrict__ xf,
    const float* __restrict__ fw, const float* __restrict__ tw, const float* __restrict__ mag,
    const unsigned short* __restrict__ w0h, const unsigned short* __restrict__ w0l,
    const float* __restrict__ b0,
    const unsigned short* __restrict__ w1h, const unsigned short* __restrict__ w1l,
    const float* __restrict__ b1,
    float* __restrict__ out,
    unsigned short* __restrict__ h0hi, unsigned short* __restrict__ h0lo,
    unsigned short* __restrict__ h1hi, unsigned short* __restrict__ h1lo,
    float* __restrict__ c0, float* __restrict__ c1,
    int* __restrict__ slots, int* __restrict__ go) {
  extern __shared__ char lds[];
  f32x4* red = reinterpret_cast<f32x4*>(lds + LO_BYTES);

  const int tid = threadIdx.x;
  const int lane = tid & 63;
  const int wv = tid >> 6;               // 0..7
  const int mt = wv & 3;                 // row subtile (16 rows)
  const int kh = wv >> 2;                // K-half
  const int l15 = lane & 15, l4 = lane >> 4;

  const int wg = blockIdx.x;
  const int layer = wg >> 7;
  const int i = wg & 127;
  const int x8 = i & 7, kk = i >> 3;     // x8 ~ XCD (wg%8 round-robin)
  const int jt = x8 * 8 + (kk >> 1);     // 0..63
  const int mg = kk & 1;
  const int jb = jt * 16;

  const int bact = mg * 64 + mt * 16 + l15;   // batch row
  const int j0 = jb + l4 * 4;

  const int K = layer ? K1 : K0;
  const unsigned short* whi = layer ? w1h : w0h;
  const unsigned short* wlo = layer ? w1l : w0l;
  const size_t off0 = (size_t)(0 * Hh + jb + l15) * K + l4 * 8;
  const size_t off1 = (size_t)(1 * Hh + jb + l15) * K + l4 * 8;
  const size_t off2 = (size_t)(2 * Hh + jb + l15) * K + l4 * 8;

  const float* bb = layer ? b1 : b0;
  const f32x4 bi = *(const f32x4*)(bb + j0);
  const f32x4 bg = *(const f32x4*)(bb + Hh + j0);
  const f32x4 bo = *(const f32x4*)(bb + 2 * Hh + j0);

  float* cst = (layer ? c1 : c0) + (size_t)bact * Hh + j0;
  float* outb = out + (size_t)bact * Ss * Hh + j0;
  const float emag = __expf(mag[0]);

  // ---- prologue: W-lo slice -> LDS  [c][g][l4][l15][16B] ----
  if constexpr (WLO) {
    const u64* wsl = (const u64*)wlo;
    const int K4 = K >> 2;
    for (int idx = tid; idx < 48 * 384; idx += 512) {
      int R = idx / 384;                 // 0..47 = g*16 + rr
      int o = idx - R * 384;             // u64 index within row (K < 1536)
      int g = R >> 4, rr = R & 15;
      u64 v = wsl[(size_t)(g * Hh + jb + rr) * K4 + o];
      *(u64*)(lds + (o >> 3) * CHUNKB + g * 1024 + ((o >> 1) & 3) * 256 +
              rr * 16 + (o & 1) * 8) = v;
    }
  }
  __syncthreads();

  for (int p = 0; p < NPH; ++p) {
    const bool act = layer ? (p >= 1) : (p < Ss);
    const int t = layer ? (p - 1) : p;
    const int rslot = (p - 1) & (RING - 1);   // read slot (written last phase)
    const int wslot = p & (RING - 1);         // write slot

    if (act) {
      f32x4 z = {0.f, 0.f, 0.f, 0.f};
      f32x4 aI0 = z, aG0 = z, aO0 = z, aI1 = z, aG1 = z, aO1 = z;
      const size_t hbase = (size_t)rslot * BH + (size_t)bact * Hh + l4 * 8;

      if (layer == 0) {
        if (kh == 0) {
          // x part: k in [0,512)
          const float* px = xf + ((size_t)bact * Ss + t) * Ii + l4 * 8;
          const float twm = tw[t] * emag;
          BLOCK4_X(px, 0);
          BLOCK4_X(px, 128);
          BLOCK4_X(px, 256);
          BLOCK4_X(px, 384);
          // h0_prev: k-offsets [0,256) -> W K [512,768)
          BLOCK8_L(h0hi + hbase, h0lo + hbase, 0, Ii);
        } else {
          // h0_prev: k-offsets [256,1024) -> W K [768,1536)
          BLOCK8_L(h0hi + hbase, h0lo + hbase, 256, Ii + 256);
          BLOCK8_L(h0hi + hbase, h0lo + hbase, 512, Ii + 512);
          BLOCK8_L(h0hi + hbase, h0lo + hbase, 768, Ii + 768);
        }
      } else {
        if (kh == 0) {
          // h0_t: W K [0,1024)
          BLOCK8_L(h0hi + hbase, h0lo + hbase, 0, 0);
          BLOCK8_L(h0hi + hbase, h0lo + hbase, 256, 256);
          BLOCK8_L(h0hi + hbase, h0lo + hbase, 512, 512);
          BLOCK8_L(h0hi + hbase, h0lo + hbase, 768, 768);
        } else {
          // h1_prev: W K [1024,1536) lo from LDS, [1536,2048) lo from global
          BLOCK8_L(h1hi + hbase, h1lo + hbase, 0, Hh);
          BLOCK8_L(h1hi + hbase, h1lo + hbase, 256, Hh + 256);
          BLOCK4_G(h1hi + hbase, h1lo + hbase, 512, Hh + 512);
          BLOCK4_G(h1hi + hbase, h1lo + hbase, 640, Hh + 640);
          BLOCK4_G(h1hi + hbase, h1lo + hbase, 768, Hh + 768);
          BLOCK4_G(h1hi + hbase, h1lo + hbase, 896, Hh + 896);
        }
      }

      if (kh == 1) {
        red[((mt * 3 + 0) << 6) + lane] = aI0 + aI1;
        red[((mt * 3 + 1) << 6) + lane] = aG0 + aG1;
        red[((mt * 3 + 2) << 6) + lane] = aO0 + aO1;
      }
      __syncthreads();
      if (kh == 0) {
        f32x4 ai = aI0 + aI1 + red[((mt * 3 + 0) << 6) + lane] + bi;
        f32x4 ag = aG0 + aG1 + red[((mt * 3 + 1) << 6) + lane] + bg;
        f32x4 ao = aO0 + aO1 + red[((mt * 3 + 2) << 6) + lane] + bo;
        f32x4 cp = *(const f32x4*)cst;
        f32x4 cn, hn;
        u64 hpk = 0, lpk = 0;
#pragma unroll
        for (int r = 0; r < 4; ++r) {
          float f = sig_(cp[r]);                   // forget gate from c_prev (quirk)
          float cc = f * cp[r] + sig_(ai[r]) * tanh_(ag[r]);
          float hh = sig_(ao[r]) * tanh_(cc) * f;  // extra *f (quirk)
          cn[r] = cc; hn[r] = hh;
          unsigned short hi = bf16r(hh);
          hpk |= (u64)hi << (16 * r);
          lpk |= (u64)bf16r(hh - bf2f(hi)) << (16 * r);
        }
        *(f32x4*)cst = cn;
        // sc1 write-through stores -> LLC (consumers first-touch from LLC)
        const size_t wbase = (size_t)wslot * BH + (size_t)bact * Hh + j0;
        __hip_atomic_store((u64*)((layer ? h1hi : h0hi) + wbase), hpk,
                           __ATOMIC_RELAXED, __HIP_MEMORY_SCOPE_AGENT);
        __hip_atomic_store((u64*)((layer ? h1lo : h0lo) + wbase), lpk,
                           __ATOMIC_RELAXED, __HIP_MEMORY_SCOPE_AGENT);
        if (layer) {
          *(f32x4*)(outb + (size_t)t * Hh) = hn;
          if (t == Ss - 1) {
            *(f32x4*)(out + OF_H1 + (size_t)bact * Hh + j0) = hn;
            *(f32x4*)(out + OF_C1 + (size_t)bact * Hh + j0) = cn;
          }
        } else if (t == Ss - 1) {
          *(f32x4*)(out + OF_H0 + (size_t)bact * Hh + j0) = hn;
          *(f32x4*)(out + OF_C0 + (size_t)bact * Hh + j0) = cn;
        }
      }
    }

    // ---- grid barrier (master-WG style, no per-phase fences) ----
    if (p < NPH - 1) {
      __syncthreads();   // drains vmcnt: stores reached coherence point
      if (wg == 0) {
        if (tid == 0)
          __hip_atomic_store(&slots[0], p + 1, __ATOMIC_RELAXED, __HIP_MEMORY_SCOPE_AGENT);
        int gd = 0; bool ok;
        do {
          ok = true;
          if (tid < 256)
            ok = __hip_atomic_load(&slots[tid], __ATOMIC_RELAXED, __HIP_MEMORY_SCOPE_AGENT) > p;
          if (!ok) __builtin_amdgcn_s_sleep(1);
        } while (!__syncthreads_and(ok) && ++gd < (1 << 22));
        if (tid == 0)
          __hip_atomic_store(go, p + 1, __ATOMIC_RELAXED, __HIP_MEMORY_SCOPE_AGENT);
      } else {
        if (tid == 0) {
          __hip_atomic_store(&slots[wg], p + 1, __ATOMIC_RELAXED, __HIP_MEMORY_SCOPE_AGENT);
          int gd = 0;
          while (__hip_atomic_load(go, __ATOMIC_RELAXED, __HIP_MEMORY_SCOPE_AGENT) <= p &&
                 ++gd < (1 << 24))
            __builtin_amdgcn_s_sleep(1);
        }
        __syncthreads();
      }
      // ring-boundary coherence: one acquire-inv per RING phases (stale
      // window = ring depth). W-hi refetches from LLC only here.
      if ((p & (RING - 1)) == (RING - 1)) {
        if (tid == 0) __builtin_amdgcn_fence(__ATOMIC_ACQUIRE, "agent");
        __syncthreads();
      }
    }
  }
}

// ---------------------------------------------------------------------------
extern "C" void kernel_launch(void* const* d_in, const int* in_sizes, int n_in,
                              void* d_out, int out_size, void* d_ws, size_t ws_size,
                              hipStream_t stream) {
  const float* x   = (const float*)d_in[0];
  const float* fw  = (const float*)d_in[1];
  const float* tw  = (const float*)d_in[2];
  const float* mag = (const float*)d_in[3];
  const float* W0  = (const float*)d_in[4];
  const float* b0  = (const float*)d_in[5];
  const float* W1  = (const float*)d_in[6];
  const float* b1  = (const float*)d_in[7];
  float* out = (float*)d_out;
  char* ws = (char*)d_ws;

  if (ws_size < WS_HIEND) return;
  const bool wlo = ws_size >= WS_NEED;

  unsigned short* w0h = (unsigned short*)(ws + WS_W0H);
  unsigned short* w1h = (unsigned short*)(ws + WS_W1H);
  unsigned short* w0l = (unsigned short*)(ws + (wlo ? WS_W0L : WS_W0H));
  unsigned short* w1l = (unsigned short*)(ws + (wlo ? WS_W1L : WS_W1H));

  (void)hipFuncSetAttribute((const void*)lstm_persist<true>,
                            hipFuncAttributeMaxDynamicSharedMemorySize, DYN_LDS);
  (void)hipFuncSetAttribute((const void*)lstm_persist<false>,
                            hipFuncAttributeMaxDynamicSharedMemorySize, DYN_LDS);

  k_zero<<<1140, 256, 0, stream>>>((uint4*)ws, (int)(WS_ZEND / 16));
  if (wlo)
    k_convert<true><<<1024, 256, 0, stream>>>(W0, W1, w0h, w0l, w1h, w1l);
  else
    k_convert<false><<<1024, 256, 0, stream>>>(W0, W1, w0h, w0l, w1h, w1l);

#define ARGS x, fw, tw, mag, w0h, w0l, b0, w1h, w1l, b1, out,                 \
    (unsigned short*)(ws + WS_H0HI), (unsigned short*)(ws + WS_H0LO),         \
    (unsigned short*)(ws + WS_H1HI), (unsigned short*)(ws + WS_H1LO),         \
    (float*)(ws + WS_C0), (float*)(ws + WS_C1),                               \
    (int*)(ws + WS_SLOTS), (int*)(ws + WS_GO)
  if (wlo)
    lstm_persist<true><<<NWG, 512, DYN_LDS, stream>>>(ARGS);
  else
    lstm_persist<false><<<NWG, 512, DYN_LDS, stream>>>(ARGS);
#undef ARGS
}

// Round 8
// 15902.101 us; speedup vs baseline: 2.9571x; 2.9571x over previous
//
#include <hip/hip_runtime.h>
#include <hip/hip_bf16.h>

// ============================================================================
// 2-layer quirky LSTM, persistent kernel, round 8.
// r7 lesson: W cannot stay L2-resident (h-ring rotation evicts it; 15MB/phase
// refetch past L2 = the 44us wall), and wave-level MLP can't hide it.
// This round: single-plane FP16 datapath (W, h, x all fp16; c stays f32).
//   - error model (measured anchors r1/r3): predicted absmax ~0.12 < 0.5325
//   - W fully in LDS for L0 (144KB) and K<1536 for L1 -> W out of L2
//   - MFMA count /3, global bytes /2.5; L2 holds only h slots + x
// Ring-16 h exchange (sc1 producer stores -> LLC, plain consumer loads,
// acquire-inv every 16 phases) and master-WG barrier unchanged from r6.
// ============================================================================

typedef __attribute__((ext_vector_type(8))) _Float16 f16x8;
typedef __attribute__((ext_vector_type(4))) float f32x4;
typedef unsigned long long u64;
#define DEV __device__ __forceinline__

namespace {
constexpr int Bb = 128, Ss = 1024, Ii = 512, Hh = 1024;
constexpr int K0 = Ii + Hh;            // 1536
constexpr int K1 = 2 * Hh;             // 2048
constexpr int NWG = 256;               // 1 WG/CU, 512 threads
constexpr int NPH = Ss + 1;
constexpr int RING = 16;               // h ring depth (= inv period)

constexpr size_t BH    = (size_t)Bb * Hh;              // 131072
constexpr size_t OF_H0 = (size_t)Bb * Ss * Hh;
constexpr size_t OF_C0 = OF_H0 + BH;
constexpr size_t OF_H1 = OF_C0 + BH;
constexpr size_t OF_C1 = OF_H1 + BH;

// workspace
constexpr size_t WS_GO    = 0;
constexpr size_t WS_SLOTS = 256;                     // 256 ints
constexpr size_t WS_C0    = 4096;                    // f32 [B][H]
constexpr size_t WS_C1    = WS_C0 + BH * 4;
constexpr size_t RINGF    = (size_t)RING * BH * 2;   // 4 MB per layer plane
constexpr size_t WS_H0F   = WS_C1 + BH * 4;          // fp16 ring [16][B][H]
constexpr size_t WS_H1F   = WS_H0F + RINGF;
constexpr size_t WS_ZEND  = WS_H1F + RINGF;          // ~9.4 MB zeroed/launch
constexpr size_t WSZ_W0   = (size_t)3 * Hh * K0 * 2; // 9.4 MB
constexpr size_t WSZ_W1   = (size_t)3 * Hh * K1 * 2; // 12.6 MB
constexpr size_t WS_W0F   = WS_ZEND;
constexpr size_t WS_W1F   = WS_W0F + WSZ_W0;
constexpr size_t WS_NEED  = WS_W1F + WSZ_W1;         // ~31.4 MB

// LDS W: [48 k-chunks][3 gates][4 l4][16 l15][16B]  (3072 B per chunk)
// wave read: lane (l4*16+l15) -> byte lane*16 within the 1KB gate block.
constexpr int CHUNKB    = 3072;
constexpr int LO_BYTES  = 48 * CHUNKB;              // 147456 (K < 1536)
constexpr int RED_BYTES = 4 * 3 * 64 * 16;          // 12288
constexpr int DYN_LDS   = LO_BYTES + RED_BYTES;     // 159744 <= 160 KiB
}

DEV unsigned short f16b(float f) {
  return __builtin_bit_cast(unsigned short, (_Float16)f);
}
DEV float sig_(float x) { return 1.f / (1.f + __expf(-x)); }
DEV float tanh_(float x) {
  float e = __expf(-2.f * fabsf(x));
  return copysignf((1.f - e) / (1.f + e), x);
}
DEV f16x8 ldh(const unsigned short* p) { return *reinterpret_cast<const f16x8*>(p); }
#define MFMAH __builtin_amdgcn_mfma_f32_16x16x32_f16

// ---------------------------------------------------------------------------
__global__ void k_zero(uint4* p, int n16) {
  for (int i = blockIdx.x * blockDim.x + threadIdx.x; i < n16; i += gridDim.x * blockDim.x)
    p[i] = make_uint4(0u, 0u, 0u, 0u);
}

// W f32 -> fp16 single plane
__global__ void k_convert(const float* __restrict__ W0, const float* __restrict__ W1,
                          unsigned short* __restrict__ w0f, unsigned short* __restrict__ w1f) {
  const long NW04 = (long)3 * Hh * K0 / 4;
  const long NW14 = (long)3 * Hh * K1 / 4;
  const long total = NW04 + NW14;
  for (long i = (long)blockIdx.x * blockDim.x + threadIdx.x; i < total;
       i += (long)gridDim.x * blockDim.x) {
    long e; const float* src; unsigned short* dst;
    if (i < NW04) { e = i * 4;          src = W0 + e; dst = w0f + e; }
    else          { e = (i - NW04) * 4; src = W1 + e; dst = w1f + e; }
    f32x4 v = *(const f32x4*)src;
    u64 pk = 0;
#pragma unroll
    for (int e2 = 0; e2 < 4; ++e2) pk |= (u64)f16b(v[e2]) << (16 * e2);
    *(u64*)dst = pk;
  }
}

// ---------------------------------------------------------------------------
// W fragment from LDS (lane-linear, conflict-free); kl multiple of 32, < 1536
#define LD_W(g, kl)                                                           \
  (*(const f16x8*)(lds + ((kl) >> 5) * CHUNKB + (g) * 1024 + l4 * 256 + l15 * 16))

// 8-chunk block, W from LDS: 8 h-loads batched, then 24 MFMAs
#define BLOCK8_L(hP, kaB, koB)                                                \
  do {                                                                        \
    f16x8 aH[8];                                                              \
    _Pragma("unroll") for (int c8 = 0; c8 < 8; ++c8)                          \
      aH[c8] = ldh((hP) + (kaB) + c8 * 32);                                   \
    _Pragma("unroll") for (int c8 = 0; c8 < 8; ++c8) {                        \
      const int ko_ = (koB) + c8 * 32;                                        \
      f32x4 &I = (c8 & 1) ? aI1 : aI0;                                        \
      f32x4 &G = (c8 & 1) ? aG1 : aG0;                                        \
      f32x4 &O = (c8 & 1) ? aO1 : aO0;                                        \
      I = MFMAH(LD_W(0, ko_), aH[c8], I, 0, 0, 0);                            \
      G = MFMAH(LD_W(1, ko_), aH[c8], G, 0, 0, 0);                            \
      O = MFMAH(LD_W(2, ko_), aH[c8], O, 0, 0, 0);                            \
    }                                                                         \
  } while (0)

// 4-chunk block, W from global (L1 K-tail >= 1536): 16 loads batched
#define BLOCK4_G(hP, kaB, koB)                                                \
  do {                                                                        \
    f16x8 aH[4], wA[4], wB[4], wC[4];                                         \
    _Pragma("unroll") for (int c4 = 0; c4 < 4; ++c4) {                        \
      const int ko_ = (koB) + c4 * 32, ka_ = (kaB) + c4 * 32;                 \
      wA[c4] = ldh(wf + off0 + ko_);                                          \
      wB[c4] = ldh(wf + off1 + ko_);                                          \
      wC[c4] = ldh(wf + off2 + ko_);                                          \
      aH[c4] = ldh((hP) + ka_);                                               \
    }                                                                         \
    _Pragma("unroll") for (int c4 = 0; c4 < 4; ++c4) {                        \
      f32x4 &I = (c4 & 1) ? aI1 : aI0;                                        \
      f32x4 &G = (c4 & 1) ? aG1 : aG0;                                        \
      f32x4 &O = (c4 & 1) ? aO1 : aO0;                                        \
      I = MFMAH(wA[c4], aH[c4], I, 0, 0, 0);                                  \
      G = MFMAH(wB[c4], aH[c4], G, 0, 0, 0);                                  \
      O = MFMAH(wC[c4], aH[c4], O, 0, 0, 0);                                  \
    }                                                                         \
  } while (0)

// 4-chunk x block: f32 x -> fp16 on the fly; W from LDS
#define BLOCK4_X(pxP, kB)                                                     \
  do {                                                                        \
    f32x4 x0_[4], x1_[4], f0_[4], f1_[4];                                     \
    _Pragma("unroll") for (int c4 = 0; c4 < 4; ++c4) {                        \
      const int k_ = (kB) + c4 * 32;                                          \
      x0_[c4] = *(const f32x4*)((pxP) + k_);                                  \
      x1_[c4] = *(const f32x4*)((pxP) + k_ + 4);                              \
      f0_[c4] = *(const f32x4*)(fw + k_ + l4 * 8);                            \
      f1_[c4] = *(const f32x4*)(fw + k_ + l4 * 8 + 4);                        \
    }                                                                         \
    _Pragma("unroll") for (int c4 = 0; c4 < 4; ++c4) {                        \
      const int k_ = (kB) + c4 * 32;                                          \
      f32x4 xs0 = x0_[c4] * f0_[c4] * twm, xs1 = x1_[c4] * f1_[c4] * twm;     \
      f16x8 a;                                                                \
      _Pragma("unroll") for (int e = 0; e < 4; ++e) {                         \
        a[e] = (_Float16)xs0[e];                                              \
        a[e + 4] = (_Float16)xs1[e];                                          \
      }                                                                       \
      f32x4 &I = (c4 & 1) ? aI1 : aI0;                                        \
      f32x4 &G = (c4 & 1) ? aG1 : aG0;                                        \
      f32x4 &O = (c4 & 1) ? aO1 : aO0;                                        \
      I = MFMAH(LD_W(0, k_), a, I, 0, 0, 0);                                  \
      G = MFMAH(LD_W(1, k_), a, G, 0, 0, 0);                                  \
      O = MFMAH(LD_W(2, k_), a, O, 0, 0, 0);                                  \
    }                                                                         \
  } while (0)

__global__ __launch_bounds__(512, 2) void lstm_persist(
    const float* __restrict__ xf,
    const float* __restrict__ fw, const float* __restrict__ tw, const float* __restrict__ mag,
    const unsigned short* __restrict__ w0f, const float* __restrict__ b0,
    const unsigned short* __restrict__ w1f, const float* __restrict__ b1,
    float* __restrict__ out,
    unsigned short* __restrict__ h0f, unsigned short* __restrict__ h1f,
    float* __restrict__ c0, float* __restrict__ c1,
    int* __restrict__ slots, int* __restrict__ go) {
  extern __shared__ char lds[];
  f32x4* red = reinterpret_cast<f32x4*>(lds + LO_BYTES);

  const int tid = threadIdx.x;
  const int lane = tid & 63;
  const int wv = tid >> 6;               // 0..7
  const int mt = wv & 3;                 // row subtile (16 rows)
  const int kh = wv >> 2;                // K-half
  const int l15 = lane & 15, l4 = lane >> 4;

  const int wg = blockIdx.x;
  const int layer = wg >> 7;
  const int i = wg & 127;
  const int x8 = i & 7, kk = i >> 3;     // x8 ~ XCD (wg%8 round-robin)
  const int jt = x8 * 8 + (kk >> 1);     // 0..63
  const int mg = kk & 1;
  const int jb = jt * 16;

  const int bact = mg * 64 + mt * 16 + l15;   // batch row
  const int j0 = jb + l4 * 4;

  const int K = layer ? K1 : K0;
  const unsigned short* wf = layer ? w1f : w0f;
  const size_t off0 = (size_t)(0 * Hh + jb + l15) * K + l4 * 8;
  const size_t off1 = (size_t)(1 * Hh + jb + l15) * K + l4 * 8;
  const size_t off2 = (size_t)(2 * Hh + jb + l15) * K + l4 * 8;

  const float* bb = layer ? b1 : b0;
  const f32x4 bi = *(const f32x4*)(bb + j0);
  const f32x4 bg = *(const f32x4*)(bb + Hh + j0);
  const f32x4 bo = *(const f32x4*)(bb + 2 * Hh + j0);

  float* cst = (layer ? c1 : c0) + (size_t)bact * Hh + j0;
  float* outb = out + (size_t)bact * Ss * Hh + j0;
  const float emag = __expf(mag[0]);

  // ---- prologue: W K[0,1536) -> LDS  [c][g][l4][l15][16B] ----
  {
    const u64* wsl = (const u64*)wf;
    const int K4 = K >> 2;
    for (int idx = tid; idx < 48 * 384; idx += 512) {
      int R = idx / 384;                 // 0..47 = g*16 + rr
      int o = idx - R * 384;             // u64 col index (cols [0,1536))
      int g = R >> 4, rr = R & 15;
      u64 v = wsl[(size_t)(g * Hh + jb + rr) * K4 + o];
      *(u64*)(lds + (o >> 3) * CHUNKB + g * 1024 + ((o >> 1) & 3) * 256 +
              rr * 16 + (o & 1) * 8) = v;
    }
  }
  __syncthreads();

  for (int p = 0; p < NPH; ++p) {
    const bool act = layer ? (p >= 1) : (p < Ss);
    const int t = layer ? (p - 1) : p;
    const int rslot = (p - 1) & (RING - 1);   // read slot (written last phase)
    const int wslot = p & (RING - 1);         // write slot

    if (act) {
      f32x4 z = {0.f, 0.f, 0.f, 0.f};
      f32x4 aI0 = z, aG0 = z, aO0 = z, aI1 = z, aG1 = z, aO1 = z;
      const unsigned short* h0r = h0f + (size_t)rslot * BH + (size_t)bact * Hh + l4 * 8;
      const unsigned short* h1r = h1f + (size_t)rslot * BH + (size_t)bact * Hh + l4 * 8;

      if (layer == 0) {
        if (kh == 0) {
          // x part: k in [0,512), W from LDS
          const float* px = xf + ((size_t)bact * Ss + t) * Ii + l4 * 8;
          const float twm = tw[t] * emag;
          BLOCK4_X(px, 0);
          BLOCK4_X(px, 128);
          BLOCK4_X(px, 256);
          BLOCK4_X(px, 384);
          // h0_prev: k-offsets [0,256) -> W K [512,768)
          BLOCK8_L(h0r, 0, Ii);
        } else {
          // h0_prev: k-offsets [256,1024) -> W K [768,1536)
          BLOCK8_L(h0r, 256, Ii + 256);
          BLOCK8_L(h0r, 512, Ii + 512);
          BLOCK8_L(h0r, 768, Ii + 768);
        }
      } else {
        if (kh == 0) {
          // h0_t: W K [0,1024), LDS
          BLOCK8_L(h0r, 0, 0);
          BLOCK8_L(h0r, 256, 256);
          BLOCK8_L(h0r, 512, 512);
          BLOCK8_L(h0r, 768, 768);
        } else {
          // h1_prev: W K [1024,1536) LDS, [1536,2048) global tail
          BLOCK8_L(h1r, 0, Hh);
          BLOCK8_L(h1r, 256, Hh + 256);
          BLOCK4_G(h1r, 512, Hh + 512);
          BLOCK4_G(h1r, 640, Hh + 640);
          BLOCK4_G(h1r, 768, Hh + 768);
          BLOCK4_G(h1r, 896, Hh + 896);
        }
      }

      if (kh == 1) {
        red[((mt * 3 + 0) << 6) + lane] = aI0 + aI1;
        red[((mt * 3 + 1) << 6) + lane] = aG0 + aG1;
        red[((mt * 3 + 2) << 6) + lane] = aO0 + aO1;
      }
      __syncthreads();
      if (kh == 0) {
        f32x4 ai = aI0 + aI1 + red[((mt * 3 + 0) << 6) + lane] + bi;
        f32x4 ag = aG0 + aG1 + red[((mt * 3 + 1) << 6) + lane] + bg;
        f32x4 ao = aO0 + aO1 + red[((mt * 3 + 2) << 6) + lane] + bo;
        f32x4 cp = *(const f32x4*)cst;
        f32x4 cn, hn;
        u64 hpk = 0;
#pragma unroll
        for (int r = 0; r < 4; ++r) {
          float f = sig_(cp[r]);                   // forget gate from c_prev (quirk)
          float cc = f * cp[r] + sig_(ai[r]) * tanh_(ag[r]);
          float hh = sig_(ao[r]) * tanh_(cc) * f;  // extra *f (quirk)
          cn[r] = cc; hn[r] = hh;
          hpk |= (u64)f16b(hh) << (16 * r);
        }
        *(f32x4*)cst = cn;
        // sc1 write-through store -> LLC (consumers first-touch from LLC)
        const size_t wbase = (size_t)wslot * BH + (size_t)bact * Hh + j0;
        __hip_atomic_store((u64*)((layer ? h1f : h0f) + wbase), hpk,
                           __ATOMIC_RELAXED, __HIP_MEMORY_SCOPE_AGENT);
        if (layer) {
          *(f32x4*)(outb + (size_t)t * Hh) = hn;
          if (t == Ss - 1) {
            *(f32x4*)(out + OF_H1 + (size_t)bact * Hh + j0) = hn;
            *(f32x4*)(out + OF_C1 + (size_t)bact * Hh + j0) = cn;
          }
        } else if (t == Ss - 1) {
          *(f32x4*)(out + OF_H0 + (size_t)bact * Hh + j0) = hn;
          *(f32x4*)(out + OF_C0 + (size_t)bact * Hh + j0) = cn;
        }
      }
    }

    // ---- grid barrier (master-WG style) ----
    if (p < NPH - 1) {
      __syncthreads();   // drains vmcnt: stores reached coherence point
      if (wg == 0) {
        if (tid == 0)
          __hip_atomic_store(&slots[0], p + 1, __ATOMIC_RELAXED, __HIP_MEMORY_SCOPE_AGENT);
        int gd = 0; bool ok;
        do {
          ok = true;
          if (tid < 256)
            ok = __hip_atomic_load(&slots[tid], __ATOMIC_RELAXED, __HIP_MEMORY_SCOPE_AGENT) > p;
          if (!ok) __builtin_amdgcn_s_sleep(1);
        } while (!__syncthreads_and(ok) && ++gd < (1 << 22));
        if (tid == 0)
          __hip_atomic_store(go, p + 1, __ATOMIC_RELAXED, __HIP_MEMORY_SCOPE_AGENT);
      } else {
        if (tid == 0) {
          __hip_atomic_store(&slots[wg], p + 1, __ATOMIC_RELAXED, __HIP_MEMORY_SCOPE_AGENT);
          int gd = 0;
          while (__hip_atomic_load(go, __ATOMIC_RELAXED, __HIP_MEMORY_SCOPE_AGENT) <= p &&
                 ++gd < (1 << 24))
            __builtin_amdgcn_s_sleep(1);
        }
        __syncthreads();
      }
      // ring-boundary coherence: one acquire-inv per RING phases (stale
      // window = ring depth). W-global is tiny now, so refetch is cheap.
      if ((p & (RING - 1)) == (RING - 1)) {
        if (tid == 0) __builtin_amdgcn_fence(__ATOMIC_ACQUIRE, "agent");
        __syncthreads();
      }
    }
  }
}

// ---------------------------------------------------------------------------
extern "C" void kernel_launch(void* const* d_in, const int* in_sizes, int n_in,
                              void* d_out, int out_size, void* d_ws, size_t ws_size,
                              hipStream_t stream) {
  const float* x   = (const float*)d_in[0];
  const float* fw  = (const float*)d_in[1];
  const float* tw  = (const float*)d_in[2];
  const float* mag = (const float*)d_in[3];
  const float* W0  = (const float*)d_in[4];
  const float* b0  = (const float*)d_in[5];
  const float* W1  = (const float*)d_in[6];
  const float* b1  = (const float*)d_in[7];
  float* out = (float*)d_out;
  char* ws = (char*)d_ws;

  if (ws_size < WS_NEED) return;

  unsigned short* w0f = (unsigned short*)(ws + WS_W0F);
  unsigned short* w1f = (unsigned short*)(ws + WS_W1F);

  (void)hipFuncSetAttribute((const void*)lstm_persist,
                            hipFuncAttributeMaxDynamicSharedMemorySize, DYN_LDS);

  k_zero<<<2320, 256, 0, stream>>>((uint4*)ws, (int)(WS_ZEND / 16));
  k_convert<<<1024, 256, 0, stream>>>(W0, W1, w0f, w1f);

  lstm_persist<<<NWG, 512, DYN_LDS, stream>>>(
      x, fw, tw, mag, w0f, b0, w1f, b1, out,
      (unsigned short*)(ws + WS_H0F), (unsigned short*)(ws + WS_H1F),
      (float*)(ws + WS_C0), (float*)(ws + WS_C1),
      (int*)(ws + WS_SLOTS), (int*)(ws + WS_GO));
}